// Round 1
// baseline (182.993 us; speedup 1.0000x reference)
//
#include <hip/hip_runtime.h>
#include <math.h>

// FeatureWeightNet fused kernel (MI355X / gfx950)
// B=2, C=64, H=512, W=640, NB=9, G=8 (shapes fixed by the reference setup).
//
// Per pixel:
//   acc[c] = sum_s 0.5*off[s]*F[c, h+4(sy-1), w+4(sx-1)]   (reflect-pad)
//          + sum_s 0.5*off[s+9]*F[c, h+2(sy-1), w+2(sx-1)]
//   x[g]   = mean_{c in group g} acc[c]          (8 groups of 8)
//   y0 = relu(bn0(W0 x)); y1 = relu(bn1(W1 y0)); sim = ws.y1 + bs
//   out0 = sigmoid(sim); out1 = acc

#define EPSV 1e-5f

__global__ __launch_bounds__(256) void fwn_kernel(
    const float* __restrict__ F,    // [B,64,H,W]
    const float* __restrict__ off,  // [B,18,H,W]
    const float* __restrict__ w0, const float* __restrict__ b0,
    const float* __restrict__ g0, const float* __restrict__ beta0,
    const float* __restrict__ m0, const float* __restrict__ v0,
    const float* __restrict__ w1, const float* __restrict__ b1,
    const float* __restrict__ g1, const float* __restrict__ beta1,
    const float* __restrict__ m1, const float* __restrict__ v1,
    const float* __restrict__ ws, const float* __restrict__ bs,
    float* __restrict__ sig,        // [B,H,W]
    float* __restrict__ accp,       // [B,64,H,W]
    int B, int C, int H, int W)
{
    const int tx = threadIdx.x & 63;
    const int ty = threadIdx.x >> 6;
    const int w = blockIdx.x * 64 + tx;
    const int h = blockIdx.y * 4 + ty;
    const int b = blockIdx.z;
    const int HW = H * W;

    // reflected rows/cols for shifts {-4,-2,0,2,4}
    int rowoff[5], col[5];
    #pragma unroll
    for (int k = 0; k < 5; ++k) {
        int d = 2 * k - 4;
        int hh = h + d; if (hh < 0) hh = -hh; if (hh >= H) hh = 2 * H - 2 - hh;
        rowoff[k] = hh * W;
        int wk = w + d; if (wk < 0) wk = -wk; if (wk >= W) wk = 2 * W - 2 - wk;
        col[k] = wk;
    }

    // 18 tap element-offsets (per-lane, 32-bit) relative to channel base
    int tb[9], ts[9];
    #pragma unroll
    for (int sy = 0; sy < 3; ++sy) {
        #pragma unroll
        for (int sx = 0; sx < 3; ++sx) {
            tb[sy * 3 + sx] = rowoff[2 * sy] + col[2 * sx];      // shifts {-4,0,4}
            ts[sy * 3 + sx] = rowoff[sy + 1] + col[sx + 1];      // shifts {-2,0,2}
        }
    }

    // per-pixel weights, pre-scaled by 0.5 (shared across all 64 channels)
    const float* ob_ptr = off + (size_t)b * 18 * HW + h * W + w;
    float ob[9], os[9];
    #pragma unroll
    for (int s = 0; s < 9; ++s) {
        ob[s] = 0.5f * ob_ptr[(size_t)s * HW];
        os[s] = 0.5f * ob_ptr[(size_t)(s + 9) * HW];
    }

    const int pix = h * W + w;
    const float* fb = F + (size_t)b * C * HW;
    float* ab = accp + (size_t)b * C * HW + pix;

    float x[8];
    #pragma unroll
    for (int g = 0; g < 8; ++g) {
        float gs = 0.f;
        #pragma unroll
        for (int cc = 0; cc < 8; ++cc) {
            const int c = g * 8 + cc;
            const float* cb = fb + (size_t)c * HW;   // uniform base (SGPR)
            float a = 0.f;
            #pragma unroll
            for (int s = 0; s < 9; ++s) {
                a += ob[s] * cb[tb[s]];
                a += os[s] * cb[ts[s]];
            }
            __builtin_nontemporal_store(a, ab + (size_t)c * HW); // write-once stream
            gs += a;
        }
        x[g] = gs * 0.125f;
    }

    // ---- fused BN+MLP head (all-uniform weights -> scalar loads) ----
    float y0[16];
    #pragma unroll
    for (int o = 0; o < 16; ++o) {
        const float s0 = g0[o] * rsqrtf(v0[o] + EPSV);
        float z = 0.f;
        #pragma unroll
        for (int i = 0; i < 8; ++i) z += w0[o * 8 + i] * x[i];
        z = z * s0 + (b0[o] - m0[o]) * s0 + beta0[o];
        y0[o] = fmaxf(z, 0.f);
    }
    float y1[8];
    #pragma unroll
    for (int o = 0; o < 8; ++o) {
        const float s1 = g1[o] * rsqrtf(v1[o] + EPSV);
        float z = 0.f;
        #pragma unroll
        for (int i = 0; i < 16; ++i) z += w1[o * 16 + i] * y0[i];
        z = z * s1 + (b1[o] - m1[o]) * s1 + beta1[o];
        y1[o] = fmaxf(z, 0.f);
    }
    float sm = bs[0];
    #pragma unroll
    for (int i = 0; i < 8; ++i) sm += ws[i] * y1[i];
    sig[(size_t)b * HW + pix] = 1.f / (1.f + __expf(-sm));
}

extern "C" void kernel_launch(void* const* d_in, const int* in_sizes, int n_in,
                              void* d_out, int out_size, void* d_ws, size_t ws_size,
                              hipStream_t stream) {
    const float* F    = (const float*)d_in[0];
    const float* off  = (const float*)d_in[1];
    const float* w0   = (const float*)d_in[2];
    const float* b0   = (const float*)d_in[3];
    const float* g0   = (const float*)d_in[4];
    const float* bt0  = (const float*)d_in[5];
    const float* m0   = (const float*)d_in[6];
    const float* v0   = (const float*)d_in[7];
    const float* w1   = (const float*)d_in[8];
    const float* b1   = (const float*)d_in[9];
    const float* g1   = (const float*)d_in[10];
    const float* bt1  = (const float*)d_in[11];
    const float* m1   = (const float*)d_in[12];
    const float* v1   = (const float*)d_in[13];
    const float* ws   = (const float*)d_in[14];
    const float* bs   = (const float*)d_in[15];

    const int B = 2, C = 64, H = 512, W = 640;
    float* sig  = (float*)d_out;                  // [B,H,W]
    float* accp = sig + (size_t)B * H * W;        // [B,C,H,W]

    dim3 grid(W / 64, H / 4, B);
    fwn_kernel<<<grid, dim3(256), 0, stream>>>(
        F, off, w0, b0, g0, bt0, m0, v0,
        w1, b1, g1, bt1, m1, v1, ws, bs,
        sig, accp, B, C, H, W);
}